// Round 4
// baseline (34.039 us; speedup 1.0000x reference)
//
#include <hip/hip_runtime.h>
#include <hip/hip_cooperative_groups.h>

namespace cg = cooperative_groups;

// LinearClassification: loss = -2 * sum_i out[i, label[i]] / (B * V)
// B = 4096, V = 50257 -> 4096 scattered fp32 gathers + scalar reduce.
// Latency-bound, single graph node. 16 blocks (16 CUs) parallelize the
// scattered-address issue; cooperative grid.sync gives a deterministic
// cross-block reduce with NO workspace-state dependence (no counter, no
// memset node). fp64 accumulation in fixed order -> bit-deterministic.

#define BLOCK 256

__global__ __launch_bounds__(BLOCK)
void LinearClassification_71167608095256_kernel(const float* __restrict__ outm,
                                                const int* __restrict__ lab32,
                                                float* __restrict__ res,
                                                double* __restrict__ partials,
                                                int B, long long V) {
    const int tid  = threadIdx.x;
    const int bid  = blockIdx.x;
    const int gtid = bid * BLOCK + tid;
    const int lane = tid & 63;
    const int wave = tid >> 6;

    __shared__ int    s_is64;
    __shared__ double s_part[BLOCK / 64];

    // --- Layout detection (same 64 odd words in every block -> L2 broadcast).
    // int64-LE label layout => odd 32-bit words are zero high-halves;
    // int32 layout => random labels in [0, 50257): P(all 64 zero) ~ 0.
    int nonzero = 0;
    if (wave == 0) {
        int j = 2 * lane + 1;
        if (j < B) nonzero = (lab32[j] != 0);
    }

    // --- Speculative int32-layout label load + gather, issued before the
    // detection resolves (word gtid < B is in-bounds under either layout;
    // the speculative index is a valid label or 0 -> gather in-bounds).
    int   labv = 0;
    float gv   = 0.0f;
    if (gtid < B) {
        labv = lab32[gtid];
        gv   = outm[(long long)gtid * V + (long long)labv];
    }

    if (wave == 0) {
        unsigned long long ball = __ballot(nonzero);
        if (lane == 0) s_is64 = (ball == 0ull) ? 1 : 0;
    }
    __syncthreads();

    double acc = 0.0;
    if (gtid < B) {
        if (!s_is64) {
            acc = (double)gv;                      // fast path: int32 labels
        } else {                                   // int64 layout: re-gather
            const long long idx = (long long)lab32[2 * gtid];
            acc = (double)outm[(long long)gtid * V + idx];
        }
    }

    // --- Block reduction: wave shuffle tree, then LDS across 4 waves.
    #pragma unroll
    for (int off = 32; off > 0; off >>= 1)
        acc += __shfl_down(acc, off, 64);
    if (lane == 0) s_part[wave] = acc;
    __syncthreads();

    if (tid == 0) {
        double t = 0.0;
        #pragma unroll
        for (int w = 0; w < BLOCK / 64; ++w) t += s_part[w];
        // Agent-scope release store: visible across XCDs after grid.sync.
        __hip_atomic_store((unsigned long long*)&partials[bid],
                           __builtin_bit_cast(unsigned long long, t),
                           __ATOMIC_RELEASE, __HIP_MEMORY_SCOPE_AGENT);
    }

    cg::this_grid().sync();

    if (bid == 0 && tid == 0) {
        // Fixed index order -> bit-deterministic regardless of block timing.
        double t2 = 0.0;
        const int nb = (int)gridDim.x;
        for (int b = 0; b < nb; ++b) {
            unsigned long long u = __hip_atomic_load(
                (unsigned long long*)&partials[b],
                __ATOMIC_ACQUIRE, __HIP_MEMORY_SCOPE_AGENT);
            t2 += __builtin_bit_cast(double, u);
        }
        res[0] = (float)(-2.0 * t2 / ((double)B * (double)V));
    }
}

extern "C" void kernel_launch(void* const* d_in, const int* in_sizes, int n_in,
                              void* d_out, int out_size, void* d_ws, size_t ws_size,
                              hipStream_t stream) {
    const float* outm = (const float*)d_in[0];
    const int*   lab  = (const int*)d_in[1];
    float*       res  = (float*)d_out;

    int B = in_sizes[1];                             // 4096
    long long V = (long long)in_sizes[0] / B;        // 50257
    int nblocks = (B + BLOCK - 1) / BLOCK;           // 16

    double* partials = (double*)d_ws;                // written fresh each call

    void* args[] = { (void*)&outm, (void*)&lab, (void*)&res,
                     (void*)&partials, (void*)&B, (void*)&V };
    hipLaunchCooperativeKernel(
        (void*)LinearClassification_71167608095256_kernel,
        dim3(nblocks), dim3(BLOCK), args, 0, stream);
}

// Round 5
// 9.858 us; speedup vs baseline: 3.4531x; 3.4531x over previous
//
#include <hip/hip_runtime.h>

// LinearClassification: loss = -2 * sum_i out[i, label[i]] / (B * V)
// B = 4096, V = 50257. Only 4096 scattered fp32 gathers matter. Latency-bound:
// structure so ALL memory ops (layout-detect loads, label loads, gathers) are
// in flight concurrently, with no dependent chains. fp64 accumulation keeps
// summation error ~1e-15 vs the 8e-9 absolute threshold.
//
// Session model (R0-R4): dur_us ~= 8.5-9us fixed single-node graph-replay
// overhead + ~1us kernel time. Multi-block variants (extra memset node: +6us;
// cooperative launch: +24us) cost more in node overhead than the <=1us of
// single-CU address-issue serialization they could recover. Single block,
// single plain launch node is the measured optimum (9.67us, R2).

__global__ __launch_bounds__(1024)
void LinearClassification_71167608095256_kernel(const float* __restrict__ outm,
                                                const int* __restrict__ lab32,
                                                float* __restrict__ res,
                                                int B, long long V) {
    const int tid      = threadIdx.x;
    const int nthreads = blockDim.x;
    const int lane     = tid & 63;
    const int wave     = tid >> 6;
    const int nwaves   = (nthreads + 63) >> 6;

    __shared__ int    s_nz[16];
    __shared__ int    s_is64;
    __shared__ double s_part[16];

    constexpr int MAXI = 8;                    // supports B <= 8 * nthreads

    // ---- Issue ALL loads up front, independent of each other ----

    // (a) layout-detection loads: odd 32-bit words among the first B words.
    //     int64-LE layout => all are zero high-halves; int32 => random labels.
    int nonzero = 0;
    #pragma unroll
    for (int k = 0; k < MAXI / 2; ++k) {
        int j = 2 * (tid + k * nthreads) + 1;
        if (j < B) nonzero |= (lab32[j] != 0);
    }

    // (b) speculative int32-layout label loads (word i is in-bounds for both
    //     layouts since i < B).
    int labv[MAXI];
    #pragma unroll
    for (int k = 0; k < MAXI; ++k) {
        int i = tid + k * nthreads;
        if (i < B) labv[k] = lab32[i];
    }

    // (c) speculative gathers. Under int64 layout labv[k] is either a valid
    //     label (< V) or 0 -> always in-bounds; values discarded in that case.
    float gv[MAXI];
    #pragma unroll
    for (int k = 0; k < MAXI; ++k) {
        int i = tid + k * nthreads;
        if (i < B) gv[k] = outm[(long long)i * V + labv[k]];
    }

    // ---- Resolve detection (overlapped with the loads above) ----
    unsigned long long ball = __ballot(nonzero);
    if (lane == 0) s_nz[wave] = (ball != 0ull) ? 1 : 0;
    __syncthreads();
    if (tid == 0) {
        int nz = 0;
        for (int w = 0; w < nwaves; ++w) nz |= s_nz[w];
        s_is64 = (nz == 0);   // all odd words zero -> int64 layout
    }
    __syncthreads();

    // ---- Accumulate (fast path: int32 layout, speculation valid) ----
    double acc = 0.0;
    if (!s_is64) {
        #pragma unroll
        for (int k = 0; k < MAXI; ++k) {
            int i = tid + k * nthreads;
            if (i < B) acc += (double)gv[k];
        }
    } else {
        // Slow path (int64 layout): reload correct indices, re-gather.
        int lv[MAXI];
        #pragma unroll
        for (int k = 0; k < MAXI; ++k) {
            int i = tid + k * nthreads;
            if (i < B) lv[k] = lab32[2 * i];
        }
        #pragma unroll
        for (int k = 0; k < MAXI; ++k) {
            int i = tid + k * nthreads;
            if (i < B) acc += (double)outm[(long long)i * V + lv[k]];
        }
    }

    // ---- Deterministic reduction: wave shuffle tree, then LDS ----
    #pragma unroll
    for (int off = 32; off > 0; off >>= 1)
        acc += __shfl_down(acc, off, 64);
    if (lane == 0) s_part[wave] = acc;
    __syncthreads();
    if (tid == 0) {
        double t = 0.0;
        for (int w = 0; w < nwaves; ++w) t += s_part[w];
        res[0] = (float)(-2.0 * t / ((double)B * (double)V));
    }
}

extern "C" void kernel_launch(void* const* d_in, const int* in_sizes, int n_in,
                              void* d_out, int out_size, void* d_ws, size_t ws_size,
                              hipStream_t stream) {
    const float* outm = (const float*)d_in[0];
    const int*   lab  = (const int*)d_in[1];
    float*       res  = (float*)d_out;

    const int B = in_sizes[1];                       // 4096
    const long long V = (long long)in_sizes[0] / B;  // 50257

    LinearClassification_71167608095256_kernel<<<1, 1024, 0, stream>>>(
        outm, lab, res, B, V);
}